// Round 1
// baseline (53.829 us; speedup 1.0000x reference)
//
#include <hip/hip_runtime.h>

// SkeLossMultiClass: fused streaming reduction.
// B=2, C=4, D=64, H=256, W=256; classes 1..3; BETA=25, EPS=1e-4.
// num_c  = sum p_c * (v==c) * (0.1 + (s==c))
// den1_c = sum p_c * (1.1 - (v==c) + (s==c))
// den2_c = sum (v==c) * (0.1 + (s==c))
// loss = -mean_b( sum_c score_bc / 3 ),  score = (26*num+eps)/(den1+25*den2+eps)

#define DHW (64 * 256 * 256)   // 4194304 spatial elements per (b, c)
#define NACC 9                 // num[3], den1[3], den2[3]

__global__ __launch_bounds__(256) void ske_partial_kernel(
    const float* __restrict__ out, const int* __restrict__ labels,
    float* __restrict__ ws)
{
    const int b = blockIdx.y;
    const float* p1 = out + ((size_t)(b * 4 + 1)) * DHW;
    const float* p2 = out + ((size_t)(b * 4 + 2)) * DHW;
    const float* p3 = out + ((size_t)(b * 4 + 3)) * DHW;
    const int* ves = labels + (size_t)(b * 2) * DHW;
    const int* ske = ves + DHW;

    float acc[NACC];
#pragma unroll
    for (int k = 0; k < NACC; ++k) acc[k] = 0.f;

    const int nvec = DHW / 4;
    for (int i = blockIdx.x * blockDim.x + threadIdx.x; i < nvec;
         i += gridDim.x * blockDim.x) {
        const float4 a1 = ((const float4*)p1)[i];
        const float4 a2 = ((const float4*)p2)[i];
        const float4 a3 = ((const float4*)p3)[i];
        const int4 v4 = ((const int4*)ves)[i];
        const int4 s4 = ((const int4*)ske)[i];

        const float pv[4][3] = {{a1.x, a2.x, a3.x},
                                {a1.y, a2.y, a3.y},
                                {a1.z, a2.z, a3.z},
                                {a1.w, a2.w, a3.w}};
        const int vv[4] = {v4.x, v4.y, v4.z, v4.w};
        const int sv[4] = {s4.x, s4.y, s4.z, s4.w};

#pragma unroll
        for (int j = 0; j < 4; ++j) {
#pragma unroll
            for (int c = 0; c < 3; ++c) {
                const float ev = (vv[j] == c + 1) ? 1.f : 0.f;
                const float es = (sv[j] == c + 1) ? 1.f : 0.f;
                const float imp = 1.1f - ev + es;
                const float w = ev * (0.1f + es);   // ev*imp simplified
                acc[c]     += pv[j][c] * w;          // num
                acc[3 + c] += pv[j][c] * imp;        // den1
                acc[6 + c] += w;                     // den2
            }
        }
    }

    // wave (64-lane) shuffle reduce, then cross-wave via LDS, one atomic/block
    __shared__ float red[4][NACC];
    const int lane = threadIdx.x & 63;
    const int wid = threadIdx.x >> 6;
#pragma unroll
    for (int k = 0; k < NACC; ++k) {
        float v = acc[k];
#pragma unroll
        for (int off = 32; off > 0; off >>= 1) v += __shfl_down(v, off, 64);
        if (lane == 0) red[wid][k] = v;
    }
    __syncthreads();
    if (wid == 0 && lane < NACC) {
        const float v = red[0][lane] + red[1][lane] + red[2][lane] + red[3][lane];
        atomicAdd(&ws[b * NACC + lane], v);
    }
}

__global__ void ske_final_kernel(const float* __restrict__ ws,
                                 float* __restrict__ out)
{
    if (threadIdx.x == 0 && blockIdx.x == 0) {
        float loss = 0.f;
#pragma unroll
        for (int b = 0; b < 2; ++b) {
            float ssum = 0.f;
#pragma unroll
            for (int c = 0; c < 3; ++c) {
                const float num  = ws[b * NACC + c];
                const float den1 = ws[b * NACC + 3 + c];
                const float den2 = ws[b * NACC + 6 + c];
                ssum += (26.f * num + 1e-4f) / (den1 + 25.f * den2 + 1e-4f);
            }
            loss += ssum * (1.f / 3.f);
        }
        out[0] = -loss * 0.5f;
    }
}

extern "C" void kernel_launch(void* const* d_in, const int* in_sizes, int n_in,
                              void* d_out, int out_size, void* d_ws, size_t ws_size,
                              hipStream_t stream) {
    const float* out_probs = (const float*)d_in[0];
    const int* labels = (const int*)d_in[1];
    float* ws = (float*)d_ws;

    // ws is poisoned (0xAA) once and never re-poisoned: zero it every call.
    hipMemsetAsync(ws, 0, 2 * NACC * sizeof(float), stream);

    dim3 grid(1024, 2);
    ske_partial_kernel<<<grid, 256, 0, stream>>>(out_probs, labels, ws);
    ske_final_kernel<<<1, 64, 0, stream>>>(ws, (float*)d_out);
}

// Round 2
// 45.176 us; speedup vs baseline: 1.1916x; 1.1916x over previous
//
#include <hip/hip_runtime.h>

// SkeLossMultiClass: fused streaming reduction (f32 probs + i32 labels -> scalar).
// B=2, C=4, D=64, H=256, W=256; classes 1..3; BETA=25, EPS=1e-4.
// Per element, per class c: ev=(v==c), es=(s==c)
//   num_c  += p_c * ev * (0.1+es)        (== ev*importance)
//   den1_c += p_c * (1.1 - ev + es)
//   den2_c += ev * (0.1+es)
// score = (26*num+eps)/(den1+25*den2+eps); loss = -mean_b(sum_c score/3)
// Channel 0 of probs never read (33 MB saved). Ignore-mask is a provable no-op.

#define DHW (64 * 256 * 256)   // 4194304
#define NVEC (DHW / 4)         // 1048576 float4/int4 per (b,c)
#define GX 2048
#define TPB 256
#define STRIDE (GX * TPB)      // 524288 ; NVEC / STRIDE == 2 exactly
#define NACC 9                 // num[3], den1[3], den2[3]

__global__ __launch_bounds__(TPB) void ske_partial_kernel(
    const float* __restrict__ out, const int* __restrict__ labels,
    float* __restrict__ ws)
{
    const int b = blockIdx.y;
    const int bx = blockIdx.x;
    const float4* p1 = (const float4*)(out + ((size_t)(b * 4 + 1)) * DHW);
    const float4* p2 = (const float4*)(out + ((size_t)(b * 4 + 2)) * DHW);
    const float4* p3 = (const float4*)(out + ((size_t)(b * 4 + 3)) * DHW);
    const int4* ves = (const int4*)(labels + (size_t)(b * 2) * DHW);
    const int4* ske = ves + NVEC;

    const int i0 = bx * TPB + threadIdx.x;
    const int i1 = i0 + STRIDE;

    // Issue all 10 loads up-front: max memory-level parallelism, one wait.
    const float4 a1_0 = p1[i0], a1_1 = p1[i1];
    const float4 a2_0 = p2[i0], a2_1 = p2[i1];
    const float4 a3_0 = p3[i0], a3_1 = p3[i1];
    const int4   v_0 = ves[i0], v_1 = ves[i1];
    const int4   s_0 = ske[i0], s_1 = ske[i1];

    float num[3] = {0.f, 0.f, 0.f};
    float d1[3]  = {0.f, 0.f, 0.f};
    float d2[3]  = {0.f, 0.f, 0.f};

    auto body = [&](const float4& a1, const float4& a2, const float4& a3,
                    const int4& v4, const int4& s4) {
        const float pv[4][3] = {{a1.x, a2.x, a3.x},
                                {a1.y, a2.y, a3.y},
                                {a1.z, a2.z, a3.z},
                                {a1.w, a2.w, a3.w}};
        const int vv[4] = {v4.x, v4.y, v4.z, v4.w};
        const int sv[4] = {s4.x, s4.y, s4.z, s4.w};
#pragma unroll
        for (int j = 0; j < 4; ++j) {
#pragma unroll
            for (int c = 0; c < 3; ++c) {
                const bool mv = (vv[j] == c + 1);
                const bool ms = (sv[j] == c + 1);
                const float t   = ms ? 1.1f : 0.1f;      // 0.1 + es
                const float w   = mv ? t : 0.0f;         // ev*(0.1+es)
                const float imp = mv ? t : (t + 1.0f);   // 1.1 - ev + es
                num[c] += pv[j][c] * w;
                d1[c]  += pv[j][c] * imp;
                d2[c]  += w;
            }
        }
    };
    body(a1_0, a2_0, a3_0, v_0, s_0);
    body(a1_1, a2_1, a3_1, v_1, s_1);

    // wave (64-lane) shuffle reduce, cross-wave via LDS, per-block slot write
    __shared__ float red[4][NACC];
    const int lane = threadIdx.x & 63;
    const int wid = threadIdx.x >> 6;
    float acc[NACC];
#pragma unroll
    for (int k = 0; k < 3; ++k) { acc[k] = num[k]; acc[3 + k] = d1[k]; acc[6 + k] = d2[k]; }
#pragma unroll
    for (int k = 0; k < NACC; ++k) {
        float v = acc[k];
#pragma unroll
        for (int off = 32; off > 0; off >>= 1) v += __shfl_down(v, off, 64);
        if (lane == 0) red[wid][k] = v;
    }
    __syncthreads();
    if (wid == 0 && lane < NACC) {
        const float v = red[0][lane] + red[1][lane] + red[2][lane] + red[3][lane];
        // slot layout: ws[(b*NACC + k) * GX + bx]  -> every slot written every call
        ws[((size_t)(b * NACC + lane)) * GX + bx] = v;
    }
}

__global__ __launch_bounds__(TPB) void ske_final_kernel(
    const float* __restrict__ ws, float* __restrict__ out)
{
    // reduce 18 accumulators x GX blocks (147 KB), then finalize scalar
    float acc[2 * NACC];
#pragma unroll
    for (int s = 0; s < 2 * NACC; ++s) acc[s] = 0.f;
    for (int j = threadIdx.x; j < GX; j += TPB) {
#pragma unroll
        for (int s = 0; s < 2 * NACC; ++s) acc[s] += ws[(size_t)s * GX + j];
    }
    __shared__ float red[4][2 * NACC];
    const int lane = threadIdx.x & 63;
    const int wid = threadIdx.x >> 6;
#pragma unroll
    for (int s = 0; s < 2 * NACC; ++s) {
        float v = acc[s];
#pragma unroll
        for (int off = 32; off > 0; off >>= 1) v += __shfl_down(v, off, 64);
        if (lane == 0) red[wid][s] = v;
    }
    __syncthreads();
    if (threadIdx.x == 0) {
        float tot[2 * NACC];
#pragma unroll
        for (int s = 0; s < 2 * NACC; ++s)
            tot[s] = red[0][s] + red[1][s] + red[2][s] + red[3][s];
        float loss = 0.f;
#pragma unroll
        for (int b = 0; b < 2; ++b) {
            float ssum = 0.f;
#pragma unroll
            for (int c = 0; c < 3; ++c) {
                const float n  = tot[b * NACC + c];
                const float e1 = tot[b * NACC + 3 + c];
                const float e2 = tot[b * NACC + 6 + c];
                ssum += (26.f * n + 1e-4f) / (e1 + 25.f * e2 + 1e-4f);
            }
            loss += ssum * (1.f / 3.f);
        }
        out[0] = -loss * 0.5f;
    }
}

extern "C" void kernel_launch(void* const* d_in, const int* in_sizes, int n_in,
                              void* d_out, int out_size, void* d_ws, size_t ws_size,
                              hipStream_t stream) {
    const float* out_probs = (const float*)d_in[0];
    const int* labels = (const int*)d_in[1];
    float* ws = (float*)d_ws;

    dim3 grid(GX, 2);
    ske_partial_kernel<<<grid, TPB, 0, stream>>>(out_probs, labels, ws);
    ske_final_kernel<<<1, TPB, 0, stream>>>(ws, (float*)d_out);
}

// Round 3
// 40.908 us; speedup vs baseline: 1.3159x; 1.1043x over previous
//
#include <hip/hip_runtime.h>

// SkeLossMultiClass: fused streaming reduction (f32 probs + i32 labels -> scalar).
// B=2, C=4, D=64, H=256, W=256; classes 1..3; BETA=25, EPS=1e-4.
// Per element, per class c: ev=(v==c), es=(s==c)
//   num_c  += p_c * ev * (0.1+es)
//   den1_c += p_c * (1.1 - ev + es)
//   den2_c += ev * (0.1+es)
// score = (26*num+eps)/(den1+25*den2+eps); loss = -mean_b(sum_c score/3)
// Channel 0 of probs never read (33 MB saved). Ignore-mask is a provable no-op.

#define DHW (64 * 256 * 256)   // 4194304
#define NVEC (DHW / 4)         // 1048576 float4/int4 per (b,c)
#define GX 1024
#define TPB 256
#define STRIDE (GX * TPB)      // 262144 ; NVEC / STRIDE == 4 exactly
#define NITER 4
#define NACC 9                 // num[3], den1[3], den2[3]

__global__ __launch_bounds__(TPB) void ske_partial_kernel(
    const float* __restrict__ out, const int* __restrict__ labels,
    float* __restrict__ ws)
{
    const int b = blockIdx.y;
    const int bx = blockIdx.x;
    const float4* p1 = (const float4*)(out + ((size_t)(b * 4 + 1)) * DHW);
    const float4* p2 = (const float4*)(out + ((size_t)(b * 4 + 2)) * DHW);
    const float4* p3 = (const float4*)(out + ((size_t)(b * 4 + 3)) * DHW);
    const int4* ves = (const int4*)(labels + (size_t)(b * 2) * DHW);
    const int4* ske = ves + NVEC;

    const int i0 = bx * TPB + threadIdx.x;

    // 20 independent loads; compiler schedules issue vs compute.
    float4 A1[NITER], A2[NITER], A3[NITER];
    int4 V[NITER], S[NITER];
#pragma unroll
    for (int q = 0; q < NITER; ++q) {
        const int i = i0 + q * STRIDE;
        A1[q] = p1[i];
        A2[q] = p2[i];
        A3[q] = p3[i];
        V[q] = ves[i];
        S[q] = ske[i];
    }

    float num[3] = {0.f, 0.f, 0.f};
    float d1[3]  = {0.f, 0.f, 0.f};
    float d2[3]  = {0.f, 0.f, 0.f};

#pragma unroll
    for (int q = 0; q < NITER; ++q) {
        const float pv[4][3] = {{A1[q].x, A2[q].x, A3[q].x},
                                {A1[q].y, A2[q].y, A3[q].y},
                                {A1[q].z, A2[q].z, A3[q].z},
                                {A1[q].w, A2[q].w, A3[q].w}};
        const int vv[4] = {V[q].x, V[q].y, V[q].z, V[q].w};
        const int sv[4] = {S[q].x, S[q].y, S[q].z, S[q].w};
#pragma unroll
        for (int j = 0; j < 4; ++j) {
#pragma unroll
            for (int c = 0; c < 3; ++c) {
                const bool mv = (vv[j] == c + 1);
                const bool ms = (sv[j] == c + 1);
                const float t   = ms ? 1.1f : 0.1f;      // 0.1 + es
                const float w   = mv ? t : 0.0f;         // ev*(0.1+es)
                const float imp = mv ? t : (t + 1.0f);   // 1.1 - ev + es
                num[c] += pv[j][c] * w;
                d1[c]  += pv[j][c] * imp;
                d2[c]  += w;
            }
        }
    }

    // wave (64-lane) shuffle reduce, cross-wave via LDS, per-block slot write
    __shared__ float red[4][NACC];
    const int lane = threadIdx.x & 63;
    const int wid = threadIdx.x >> 6;
    float acc[NACC];
#pragma unroll
    for (int k = 0; k < 3; ++k) { acc[k] = num[k]; acc[3 + k] = d1[k]; acc[6 + k] = d2[k]; }
#pragma unroll
    for (int k = 0; k < NACC; ++k) {
        float v = acc[k];
#pragma unroll
        for (int off = 32; off > 0; off >>= 1) v += __shfl_down(v, off, 64);
        if (lane == 0) red[wid][k] = v;
    }
    __syncthreads();
    if (wid == 0 && lane < NACC) {
        const float v = red[0][lane] + red[1][lane] + red[2][lane] + red[3][lane];
        // slot layout: ws[(b*NACC + k) * GX + bx] -> every slot written every call
        ws[((size_t)(b * NACC + lane)) * GX + bx] = v;
    }
}

__global__ __launch_bounds__(TPB) void ske_final_kernel(
    const float* __restrict__ ws, float* __restrict__ out)
{
    // 18 rows x GX floats. Thread t reads float4 #t of each row: 18 independent
    // vec loads, one wait, 18 parallel shuffle-reduces. GX == TPB*4 exactly.
    float acc[2 * NACC];
#pragma unroll
    for (int s = 0; s < 2 * NACC; ++s) {
        const float4 v = ((const float4*)(ws + (size_t)s * GX))[threadIdx.x];
        acc[s] = (v.x + v.y) + (v.z + v.w);
    }
    __shared__ float red[4][2 * NACC];
    const int lane = threadIdx.x & 63;
    const int wid = threadIdx.x >> 6;
#pragma unroll
    for (int s = 0; s < 2 * NACC; ++s) {
        float v = acc[s];
#pragma unroll
        for (int off = 32; off > 0; off >>= 1) v += __shfl_down(v, off, 64);
        if (lane == 0) red[wid][s] = v;
    }
    __syncthreads();
    if (threadIdx.x == 0) {
        float tot[2 * NACC];
#pragma unroll
        for (int s = 0; s < 2 * NACC; ++s)
            tot[s] = red[0][s] + red[1][s] + red[2][s] + red[3][s];
        float loss = 0.f;
#pragma unroll
        for (int b = 0; b < 2; ++b) {
            float ssum = 0.f;
#pragma unroll
            for (int c = 0; c < 3; ++c) {
                const float n  = tot[b * NACC + c];
                const float e1 = tot[b * NACC + 3 + c];
                const float e2 = tot[b * NACC + 6 + c];
                ssum += (26.f * n + 1e-4f) / (e1 + 25.f * e2 + 1e-4f);
            }
            loss += ssum * (1.f / 3.f);
        }
        out[0] = -loss * 0.5f;
    }
}

extern "C" void kernel_launch(void* const* d_in, const int* in_sizes, int n_in,
                              void* d_out, int out_size, void* d_ws, size_t ws_size,
                              hipStream_t stream) {
    const float* out_probs = (const float*)d_in[0];
    const int* labels = (const int*)d_in[1];
    float* ws = (float*)d_ws;

    dim3 grid(GX, 2);
    ske_partial_kernel<<<grid, TPB, 0, stream>>>(out_probs, labels, ws);
    ske_final_kernel<<<1, TPB, 0, stream>>>(ws, (float*)d_out);
}